// Round 1
// baseline (214.797 us; speedup 1.0000x reference)
//
#include <hip/hip_runtime.h>
#include <hip/hip_bf16.h>

// Problem constants (from reference)
#define NF   40   // NUM_FIELDS (f)
#define NI   40   // IN_SUB (i)
#define NN   40   // OUT_SUB (n)
#define ED   64   // EMBED_DIM (D, d)
#define NB   256  // BATCH (b)
#define TB   256  // threads per block

// ---------------------------------------------------------------------------
// Prep kernel: one block per n.
//   whT[n][d][D] = W[n][D][d] * h[n][d]      (transposed so stage-1 reads are
//                                             lane-contiguous in D)
//   alT[n][i][f] = alpha[f][i][n]            (contiguous per-n slice)
// ---------------------------------------------------------------------------
__global__ void gif_prep(const float* __restrict__ W,
                         const float* __restrict__ alpha,
                         const float* __restrict__ h,
                         float* __restrict__ whT,
                         float* __restrict__ alT) {
    const int n = blockIdx.x;
    for (int idx = threadIdx.x; idx < ED * ED; idx += TB) {
        int D = idx >> 6, d = idx & 63;
        whT[n * ED * ED + d * ED + D] = W[n * ED * ED + idx] * h[n * ED + d];
    }
    for (int idx = threadIdx.x; idx < NI * NF; idx += TB) {
        int i = idx / NF, f = idx - i * NF;
        alT[n * NI * NF + idx] = alpha[(f * NI + i) * NN + n];
    }
}

// ---------------------------------------------------------------------------
// Fused main kernel: one block per (n, b). 256 threads = 4 waves.
//   Stage 1: sT[i][D] = sum_d sBi[i][d] * sWh[d][D]     (wave w: i in [10w,10w+10))
//   Stage 2: g[i][D]  = sum_f sAl[i][f] * sB0[f][D];  out[D] = sum_i g*sT
// Broadcast operands (sBi rows, sAl rows) are wave-uniform float4 LDS reads;
// vector operands (sWh, sB0 with lane = D) are conflict-free (2 lanes/bank).
// ---------------------------------------------------------------------------
__global__ __launch_bounds__(TB) void gif_fused(
        const float* __restrict__ B0, const float* __restrict__ Bi,
        const float* __restrict__ whT, const float* __restrict__ alT,
        const float* __restrict__ W, const float* __restrict__ alpha,
        const float* __restrict__ h, int useWs,
        float* __restrict__ out) {
    const int n = blockIdx.x;   // 0..39
    const int b = blockIdx.y;   // 0..255

    __shared__ float sWh[ED][ED];   // [d][D]   16 KB
    __shared__ float sBi[NI][ED];   // [i][d]   10 KB
    __shared__ float sB0[NF][ED];   // [f][D]   10 KB
    __shared__ float sAl[NI][NF];   // [i][f]   6.25 KB (row 160B, float4-aligned)
    __shared__ float sT [NI][ED];   // [i][D]   10 KB
    __shared__ float sRed[4][ED];   //          1 KB

    const int t = threadIdx.x;

    // ---- stage 0: global -> LDS staging (coalesced float4 where possible) ----
    if (useWs) {
        const float4* src = (const float4*)(whT + n * ED * ED);
        float4* dst = (float4*)&sWh[0][0];
        for (int idx = t; idx < ED * ED / 4; idx += TB) dst[idx] = src[idx];
        const float4* asrc = (const float4*)(alT + n * NI * NF);
        float4* adst = (float4*)&sAl[0][0];
        for (int idx = t; idx < NI * NF / 4; idx += TB) adst[idx] = asrc[idx];
    } else {
        for (int idx = t; idx < ED * ED; idx += TB) {
            int D = idx >> 6, d = idx & 63;
            sWh[d][D] = W[n * ED * ED + idx] * h[n * ED + d];
        }
        for (int idx = t; idx < NI * NF; idx += TB) {
            int i = idx / NF, f = idx - i * NF;
            sAl[i][f] = alpha[(f * NI + i) * NN + n];
        }
    }
    {
        const float4* src = (const float4*)(Bi + b * NI * ED);
        float4* dst = (float4*)&sBi[0][0];
        for (int idx = t; idx < NI * ED / 4; idx += TB) dst[idx] = src[idx];
        const float4* s2 = (const float4*)(B0 + b * NF * ED);
        float4* d2 = (float4*)&sB0[0][0];
        for (int idx = t; idx < NF * ED / 4; idx += TB) d2[idx] = s2[idx];
    }
    __syncthreads();

    const int lane = t & 63;   // D
    const int w    = t >> 6;   // wave id, i-range [10w, 10w+10)

    // ---- stage 1: T[i][D] ----
    {
        float acc[10];
#pragma unroll
        for (int k = 0; k < 10; ++k) acc[k] = 0.f;
        for (int dg = 0; dg < ED / 4; ++dg) {
            const int d0 = dg * 4;
            float4 bi4[10];
#pragma unroll
            for (int k = 0; k < 10; ++k)
                bi4[k] = *(const float4*)&sBi[w * 10 + k][d0];
#pragma unroll
            for (int j = 0; j < 4; ++j) {
                const float wh = sWh[d0 + j][lane];
#pragma unroll
                for (int k = 0; k < 10; ++k)
                    acc[k] = fmaf(((const float*)&bi4[k])[j], wh, acc[k]);
            }
        }
#pragma unroll
        for (int k = 0; k < 10; ++k) sT[w * 10 + k][lane] = acc[k];
    }
    __syncthreads();

    // ---- stage 2: g[i][D] = sum_f alT[i][f]*B0[f][D]; partial = sum_i g*T ----
    {
        float g[10];
#pragma unroll
        for (int k = 0; k < 10; ++k) g[k] = 0.f;
        for (int fg = 0; fg < NF / 4; ++fg) {
            const int f0 = fg * 4;
            float4 a4[10];
#pragma unroll
            for (int k = 0; k < 10; ++k)
                a4[k] = *(const float4*)&sAl[w * 10 + k][f0];
#pragma unroll
            for (int j = 0; j < 4; ++j) {
                const float b0v = sB0[f0 + j][lane];
#pragma unroll
                for (int k = 0; k < 10; ++k)
                    g[k] = fmaf(((const float*)&a4[k])[j], b0v, g[k]);
            }
        }
        float partial = 0.f;
#pragma unroll
        for (int k = 0; k < 10; ++k)
            partial = fmaf(g[k], sT[w * 10 + k][lane], partial);
        sRed[w][lane] = partial;
    }
    __syncthreads();

    if (w == 0) {
        out[(b * NN + n) * ED + lane] =
            sRed[0][lane] + sRed[1][lane] + sRed[2][lane] + sRed[3][lane];
    }
}

extern "C" void kernel_launch(void* const* d_in, const int* in_sizes, int n_in,
                              void* d_out, int out_size, void* d_ws, size_t ws_size,
                              hipStream_t stream) {
    const float* B0    = (const float*)d_in[0];  // (256,40,64)
    const float* Bi    = (const float*)d_in[1];  // (256,40,64)
    const float* W     = (const float*)d_in[2];  // (40,64,64)
    const float* alpha = (const float*)d_in[3];  // (40,40,40)
    const float* h     = (const float*)d_in[4];  // (40,64,1)
    float* out = (float*)d_out;                  // (256,40,64)

    const size_t need = (size_t)(NN * ED * ED + NN * NI * NF) * sizeof(float);
    const int useWs = (ws_size >= need) ? 1 : 0;
    float* whT = (float*)d_ws;
    float* alT = whT + NN * ED * ED;

    if (useWs) {
        gif_prep<<<NN, TB, 0, stream>>>(W, alpha, h, whT, alT);
    }
    dim3 grid(NN, NB);
    gif_fused<<<grid, TB, 0, stream>>>(B0, Bi, whT, alT, W, alpha, h, useWs, out);
}

// Round 2
// 114.694 us; speedup vs baseline: 1.8728x; 1.8728x over previous
//
#include <hip/hip_runtime.h>
#include <hip/hip_bf16.h>

// Problem constants
#define NF 40   // fields f
#define NI 40   // in_sub i
#define NN 40   // out_sub n
#define ED 64   // embed D, d
#define NB 256  // batch b

#define PS 72            // padded K-stride (bf16 elems): 144 B rows -> even LDS banks
#define WH_N (ED * PS)   // 4608 elems per n  (Wh[n][D][d], B^T layout for stage 1)
#define AL_N (48 * PS)   // 3456 elems per n  (al[n][i][f],  A layout for stage 2)

typedef __attribute__((ext_vector_type(8))) short   short8;
typedef __attribute__((ext_vector_type(8))) __bf16  bf16x8;
typedef __attribute__((ext_vector_type(4))) float   f32x4;

__device__ __forceinline__ unsigned short f2bf(float x) {
    union { float f; unsigned u; } v; v.f = x;
    unsigned r = v.u + 0x7FFFu + ((v.u >> 16) & 1u);   // RNE
    return (unsigned short)(r >> 16);
}

__device__ __forceinline__ bf16x8 ld_frag(const unsigned short* p) {
    return __builtin_bit_cast(bf16x8, *(const short8*)p);
}

__device__ __forceinline__ f32x4 mfma16(bf16x8 a, bf16x8 b, f32x4 c) {
    return __builtin_amdgcn_mfma_f32_16x16x32_bf16(a, b, c, 0, 0, 0);
}

// --------------------------------------------------------------------------
// Prep: bf16 params into ws.
//   whp[n][D][d] = bf16(W[n][D][d] * h[n][d])   rows D, padded stride 72
//   alp[n][i][f] = bf16(alpha[f][i][n])         rows i (pad i>=40, f>=40 -> 0)
// --------------------------------------------------------------------------
__global__ __launch_bounds__(256) void gif_prep(
        const float* __restrict__ W, const float* __restrict__ alpha,
        const float* __restrict__ h,
        unsigned short* __restrict__ whp, unsigned short* __restrict__ alp) {
    const int n = blockIdx.x;
    const int t0 = blockIdx.y * 256 + threadIdx.x;   // 1024 threads across y
    for (int idx = t0; idx < ED * PS; idx += 1024) {
        int D = idx / PS, c = idx - D * PS;
        float v = (c < ED) ? W[n * ED * ED + D * ED + c] * h[n * ED + c] : 0.f;
        whp[n * WH_N + idx] = f2bf(v);
    }
    for (int idx = t0; idx < 48 * PS; idx += 1024) {
        int i = idx / PS, c = idx - i * PS;
        float v = (i < NI && c < NF) ? alpha[(c * NI + i) * NN + n] : 0.f;
        alp[n * AL_N + idx] = f2bf(v);
    }
}

// Fallback fragment builders (used only if ws too small) -------------------
__device__ __forceinline__ bf16x8 mk_al_frag(const float* __restrict__ alpha,
        int n, int m, int s, int l15, int quad) {
    bf16x8 r;
    const int row = m * 16 + l15;
    const int f0 = s * 32 + quad * 8;
#pragma unroll
    for (int j = 0; j < 8; ++j) {
        const int f = f0 + j;
        float v = (row < NI && f < NF) ? alpha[(f * NI + row) * NN + n] : 0.f;
        r[j] = (__bf16)v;
    }
    return r;
}
__device__ __forceinline__ bf16x8 mk_wh_frag(const float* __restrict__ W,
        const float* __restrict__ h, int n, int tt, int s, int l15, int quad) {
    bf16x8 r;
    const int row = tt * 16 + l15;        // D
    const int k0 = s * 32 + quad * 8;     // d  (always < 64)
#pragma unroll
    for (int j = 0; j < 8; ++j) {
        float v = W[n * ED * ED + row * ED + k0 + j] * h[n * ED + k0 + j];
        r[j] = (__bf16)v;
    }
    return r;
}

// --------------------------------------------------------------------------
// Main: grid = 5*256 blocks. block = (q = bx>>8, b = bx&255), 4 waves.
// Wave w computes (b, n) for n = q*8 + w and q*8 + w + 4, full 40x64 tile:
//   T = Bi[b](48x64) x Wh[n]^T          (2 MFMA / (Mtile,Ntile))
//   G = al[n](48x64) x B0[b]^T          (2 MFMA / (Mtile,Ntile))
//   out[D] = sum_i T*G  -> 4 reg prods + shfl_xor(16,32)
// --------------------------------------------------------------------------
__global__ __launch_bounds__(256) void gif_mfma(
        const float* __restrict__ B0, const float* __restrict__ Bi,
        const unsigned short* __restrict__ whp, const unsigned short* __restrict__ alp,
        const float* __restrict__ W, const float* __restrict__ alpha,
        const float* __restrict__ h, int useWs, float* __restrict__ out) {
    const int q = blockIdx.x >> 8;    // 0..4 -> n octet
    const int b = blockIdx.x & 255;

    __shared__ __align__(16) unsigned short sBi[48 * PS];  // A: Bi[b][i][d], pad rows 0
    __shared__ __align__(16) unsigned short sBT[ED * PS];  // B^T: B0[b]^T [D][f], pad f 0

    const int t = threadIdx.x;
    for (int idx = t; idx < 48 * PS; idx += 256) {
        int i = idx / PS, c = idx - i * PS;
        sBi[idx] = (i < NI && c < ED) ? f2bf(Bi[b * NI * ED + i * ED + c])
                                      : (unsigned short)0;
    }
    for (int idx = t; idx < ED * PS; idx += 256) {
        int D = idx / PS, c = idx - D * PS;
        sBT[idx] = (c < NF) ? f2bf(B0[b * NF * ED + c * ED + D])
                            : (unsigned short)0;
    }
    __syncthreads();

    const int lane = t & 63, w = t >> 6;
    const int quad = lane >> 4, l15 = lane & 15;
    const int fragoff = quad * 8;

    // register-cached fragments (reused across both n's)
    bf16x8 biA[3][2], b0B[4][2];
#pragma unroll
    for (int m = 0; m < 3; ++m)
#pragma unroll
        for (int s = 0; s < 2; ++s)
            biA[m][s] = ld_frag(&sBi[(m * 16 + l15) * PS + s * 32 + fragoff]);
#pragma unroll
    for (int tt = 0; tt < 4; ++tt)
#pragma unroll
        for (int s = 0; s < 2; ++s)
            b0B[tt][s] = ld_frag(&sBT[(tt * 16 + l15) * PS + s * 32 + fragoff]);

#pragma unroll
    for (int rep = 0; rep < 2; ++rep) {
        const int n = q * 8 + w + rep * 4;

        bf16x8 alA[3][2];
        if (useWs) {
#pragma unroll
            for (int m = 0; m < 3; ++m)
#pragma unroll
                for (int s = 0; s < 2; ++s)
                    alA[m][s] = ld_frag(&alp[n * AL_N + (m * 16 + l15) * PS + s * 32 + fragoff]);
        } else {
#pragma unroll
            for (int m = 0; m < 3; ++m)
#pragma unroll
                for (int s = 0; s < 2; ++s)
                    alA[m][s] = mk_al_frag(alpha, n, m, s, l15, quad);
        }

        float p[4];
#pragma unroll
        for (int tt = 0; tt < 4; ++tt) {
            bf16x8 whB[2];
            if (useWs) {
                const unsigned short* wp = &whp[n * WH_N + (tt * 16 + l15) * PS + fragoff];
                whB[0] = ld_frag(wp);
                whB[1] = ld_frag(wp + 32);
            } else {
                whB[0] = mk_wh_frag(W, h, n, tt, 0, l15, quad);
                whB[1] = mk_wh_frag(W, h, n, tt, 1, l15, quad);
            }
            float acc = 0.f;
#pragma unroll
            for (int m = 0; m < 3; ++m) {
                f32x4 z = {0.f, 0.f, 0.f, 0.f};
                f32x4 T = mfma16(biA[m][0], whB[0], z);
                T = mfma16(biA[m][1], whB[1], T);
                f32x4 G = mfma16(alA[m][0], b0B[tt][0], z);
                G = mfma16(alA[m][1], b0B[tt][1], G);
                acc += T[0] * G[0] + T[1] * G[1] + T[2] * G[2] + T[3] * G[3];
            }
            p[tt] = acc;
        }
#pragma unroll
        for (int tt = 0; tt < 4; ++tt) {
            p[tt] += __shfl_xor(p[tt], 16, 64);
            p[tt] += __shfl_xor(p[tt], 32, 64);
        }
        // lane stores element quad*16 + l15 == lane; value from p[quad]
        float v = (quad == 0) ? p[0] : (quad == 1) ? p[1] : (quad == 2) ? p[2] : p[3];
        out[(b * NN + n) * ED + lane] = v;
    }
}

extern "C" void kernel_launch(void* const* d_in, const int* in_sizes, int n_in,
                              void* d_out, int out_size, void* d_ws, size_t ws_size,
                              hipStream_t stream) {
    const float* B0    = (const float*)d_in[0];  // (256,40,64)
    const float* Bi    = (const float*)d_in[1];  // (256,40,64)
    const float* W     = (const float*)d_in[2];  // (40,64,64)
    const float* alpha = (const float*)d_in[3];  // (40,40,40)
    const float* h     = (const float*)d_in[4];  // (40,64,1)
    float* out = (float*)d_out;                  // (256,40,64)

    const size_t need = (size_t)(NN * WH_N + NN * AL_N) * sizeof(unsigned short); // 645120 B
    const int useWs = (ws_size >= need) ? 1 : 0;
    unsigned short* whp = (unsigned short*)d_ws;
    unsigned short* alp = whp + (size_t)NN * WH_N;

    if (useWs) {
        gif_prep<<<dim3(NN, 4), 256, 0, stream>>>(W, alpha, h, whp, alp);
    }
    gif_mfma<<<5 * NB, 256, 0, stream>>>(B0, Bi, whp, alp, W, alpha, h, useWs, out);
}

// Round 3
// 109.483 us; speedup vs baseline: 1.9619x; 1.0476x over previous
//
#include <hip/hip_runtime.h>
#include <hip/hip_bf16.h>

// Problem constants
#define NF 40   // fields f
#define NI 40   // in_sub i
#define NN 40   // out_sub n
#define ED 64   // embed D, d
#define NB 256  // batch b

typedef __attribute__((ext_vector_type(8))) short   short8;
typedef __attribute__((ext_vector_type(8))) __bf16  bf16x8;
typedef __attribute__((ext_vector_type(4))) float   f32x4;

__device__ __forceinline__ unsigned short f2bf(float x) {
    union { float f; unsigned u; } v; v.f = x;
    unsigned r = v.u + 0x7FFFu + ((v.u >> 16) & 1u);   // RNE
    return (unsigned short)(r >> 16);
}

__device__ __forceinline__ bf16x8 ld_frag(const unsigned short* p) {
    return __builtin_bit_cast(bf16x8, *(const short8*)p);
}

__device__ __forceinline__ f32x4 mfma16(bf16x8 a, bf16x8 b, f32x4 c) {
    return __builtin_amdgcn_mfma_f32_16x16x32_bf16(a, b, c, 0, 0, 0);
}

// ==========================================================================
// FAST PATH (tier 2): everything pre-converted to bf16 MFMA-ready layouts.
//   BiP[b][i(48)][d(64)]   = bf16(Bi[b][i][d])          (i>=40 -> 0)
//   B0T[b][D(64)][f(64)]   = bf16(B0[b][f][D])          (f>=40 -> 0)
//   whp[n][D(64)][d(64)]   = bf16(W[n][D][d]*h[n][d])
//   alp[n][i(48)][f(64)]   = bf16(alpha[f][i][n])       (pads -> 0)
// ==========================================================================
#define BIP_N (48 * 64)   // 3072
#define B0T_N (64 * 64)   // 4096
#define WHP_N (64 * 64)   // 4096
#define ALP_N (48 * 64)   // 3072

__global__ __launch_bounds__(256) void gif_prep2(
        const float* __restrict__ B0, const float* __restrict__ Bi,
        const float* __restrict__ W, const float* __restrict__ alpha,
        const float* __restrict__ h,
        unsigned short* __restrict__ BiP, unsigned short* __restrict__ B0T,
        unsigned short* __restrict__ whp, unsigned short* __restrict__ alp) {
    const int b = blockIdx.x;          // 0..255
    const int t = threadIdx.x;
    __shared__ float sB0[NF][ED + 1];  // padded transpose buffer

    for (int idx = t; idx < NF * ED; idx += 256) {
        int f = idx >> 6, D = idx & 63;
        sB0[f][D] = B0[b * NF * ED + idx];
    }
    __syncthreads();

    for (int idx = t; idx < 48 * 64; idx += 256) {   // BiP (coalesced read)
        int i = idx >> 6, d = idx & 63;
        BiP[b * BIP_N + idx] = (i < NI) ? f2bf(Bi[b * NI * ED + i * ED + d])
                                        : (unsigned short)0;
    }
    for (int idx = t; idx < 64 * 64; idx += 256) {   // B0T (transpose via LDS)
        int D = idx >> 6, f = idx & 63;
        B0T[b * B0T_N + idx] = (f < NF) ? f2bf(sB0[f][D]) : (unsigned short)0;
    }
    if (b < NN) {
        const int n = b;
        for (int idx = t; idx < 64 * 64; idx += 256) {  // whp (coalesced)
            int d = idx & 63;
            whp[n * WHP_N + idx] = f2bf(W[n * ED * ED + idx] * h[n * ED + d]);
        }
        for (int idx = t; idx < 48 * 64; idx += 256) {  // alp (gather, small)
            int i = idx >> 6, f = idx & 63;
            float v = (i < NI && f < NF) ? alpha[(f * NI + i) * NN + n] : 0.f;
            alp[n * ALP_N + idx] = f2bf(v);
        }
    }
}

// Main fast kernel: grid = 10*256 blocks, block = (q = bx>>8, b = bx&255).
// Wave w computes (b, n=q*4+w): LDS-free, all operands are direct b128
// global fragment loads from the prepped L2-resident arrays.
__global__ __launch_bounds__(256) void gif_main2(
        const unsigned short* __restrict__ BiP,
        const unsigned short* __restrict__ B0T,
        const unsigned short* __restrict__ whp,
        const unsigned short* __restrict__ alp,
        float* __restrict__ out) {
    const int q = blockIdx.x >> 8;     // 0..9
    const int b = blockIdx.x & 255;
    const int t = threadIdx.x;
    const int lane = t & 63, w = t >> 6;
    const int n = q * 4 + w;
    const int quad = lane >> 4, l15 = lane & 15, fo = quad * 8;

    const unsigned short* bip = BiP + b * BIP_N;
    const unsigned short* b0t = B0T + b * B0T_N;
    const unsigned short* wp  = whp + n * WHP_N;
    const unsigned short* ap  = alp + n * ALP_N;

    bf16x8 biA[3][2], alA[3][2], b0B[4][2], whB[4][2];
#pragma unroll
    for (int m = 0; m < 3; ++m)
#pragma unroll
        for (int s = 0; s < 2; ++s) {
            biA[m][s] = ld_frag(&bip[(m * 16 + l15) * 64 + s * 32 + fo]);
            alA[m][s] = ld_frag(&ap [(m * 16 + l15) * 64 + s * 32 + fo]);
        }
#pragma unroll
    for (int tt = 0; tt < 4; ++tt)
#pragma unroll
        for (int s = 0; s < 2; ++s) {
            b0B[tt][s] = ld_frag(&b0t[(tt * 16 + l15) * 64 + s * 32 + fo]);
            whB[tt][s] = ld_frag(&wp [(tt * 16 + l15) * 64 + s * 32 + fo]);
        }

    float p[4];
#pragma unroll
    for (int tt = 0; tt < 4; ++tt) {
        float acc = 0.f;
#pragma unroll
        for (int m = 0; m < 3; ++m) {
            f32x4 z = {0.f, 0.f, 0.f, 0.f};
            f32x4 T = mfma16(biA[m][0], whB[tt][0], z);
            T = mfma16(biA[m][1], whB[tt][1], T);
            f32x4 G = mfma16(alA[m][0], b0B[tt][0], z);
            G = mfma16(alA[m][1], b0B[tt][1], G);
            acc += T[0] * G[0] + T[1] * G[1] + T[2] * G[2] + T[3] * G[3];
        }
        p[tt] = acc;
    }
#pragma unroll
    for (int tt = 0; tt < 4; ++tt) {
        p[tt] += __shfl_xor(p[tt], 16, 64);
        p[tt] += __shfl_xor(p[tt], 32, 64);
    }
    float v = (quad == 0) ? p[0] : (quad == 1) ? p[1] : (quad == 2) ? p[2] : p[3];
    out[(b * NN + n) * ED + lane] = v;
}

// ==========================================================================
// FALLBACK (tiers 0/1): round-2 kernels, verified correct.
// ==========================================================================
#define PS 72
#define WH_N (ED * PS)
#define AL_N (48 * PS)

__global__ __launch_bounds__(256) void gif_prep(
        const float* __restrict__ W, const float* __restrict__ alpha,
        const float* __restrict__ h,
        unsigned short* __restrict__ whp, unsigned short* __restrict__ alp) {
    const int n = blockIdx.x;
    const int t0 = blockIdx.y * 256 + threadIdx.x;
    for (int idx = t0; idx < ED * PS; idx += 1024) {
        int D = idx / PS, c = idx - D * PS;
        float v = (c < ED) ? W[n * ED * ED + D * ED + c] * h[n * ED + c] : 0.f;
        whp[n * WH_N + idx] = f2bf(v);
    }
    for (int idx = t0; idx < 48 * PS; idx += 1024) {
        int i = idx / PS, c = idx - i * PS;
        float v = (i < NI && c < NF) ? alpha[(c * NI + i) * NN + n] : 0.f;
        alp[n * AL_N + idx] = f2bf(v);
    }
}

__device__ __forceinline__ bf16x8 mk_al_frag(const float* __restrict__ alpha,
        int n, int m, int s, int l15, int quad) {
    bf16x8 r;
    const int row = m * 16 + l15;
    const int f0 = s * 32 + quad * 8;
#pragma unroll
    for (int j = 0; j < 8; ++j) {
        const int f = f0 + j;
        float v = (row < NI && f < NF) ? alpha[(f * NI + row) * NN + n] : 0.f;
        r[j] = (__bf16)v;
    }
    return r;
}
__device__ __forceinline__ bf16x8 mk_wh_frag(const float* __restrict__ W,
        const float* __restrict__ h, int n, int tt, int s, int l15, int quad) {
    bf16x8 r;
    const int row = tt * 16 + l15;
    const int k0 = s * 32 + quad * 8;
#pragma unroll
    for (int j = 0; j < 8; ++j) {
        float v = W[n * ED * ED + row * ED + k0 + j] * h[n * ED + k0 + j];
        r[j] = (__bf16)v;
    }
    return r;
}

__global__ __launch_bounds__(256) void gif_mfma(
        const float* __restrict__ B0, const float* __restrict__ Bi,
        const unsigned short* __restrict__ whp, const unsigned short* __restrict__ alp,
        const float* __restrict__ W, const float* __restrict__ alpha,
        const float* __restrict__ h, int useWs, float* __restrict__ out) {
    const int q = blockIdx.x >> 8;
    const int b = blockIdx.x & 255;

    __shared__ __align__(16) unsigned short sBi[48 * PS];
    __shared__ __align__(16) unsigned short sBT[ED * PS];

    const int t = threadIdx.x;
    for (int idx = t; idx < 48 * PS; idx += 256) {
        int i = idx / PS, c = idx - i * PS;
        sBi[idx] = (i < NI && c < ED) ? f2bf(Bi[b * NI * ED + i * ED + c])
                                      : (unsigned short)0;
    }
    for (int idx = t; idx < ED * PS; idx += 256) {
        int D = idx / PS, c = idx - D * PS;
        sBT[idx] = (c < NF) ? f2bf(B0[b * NF * ED + c * ED + D])
                            : (unsigned short)0;
    }
    __syncthreads();

    const int lane = t & 63, w = t >> 6;
    const int quad = lane >> 4, l15 = lane & 15;
    const int fragoff = quad * 8;

    bf16x8 biA[3][2], b0B[4][2];
#pragma unroll
    for (int m = 0; m < 3; ++m)
#pragma unroll
        for (int s = 0; s < 2; ++s)
            biA[m][s] = ld_frag(&sBi[(m * 16 + l15) * PS + s * 32 + fragoff]);
#pragma unroll
    for (int tt = 0; tt < 4; ++tt)
#pragma unroll
        for (int s = 0; s < 2; ++s)
            b0B[tt][s] = ld_frag(&sBT[(tt * 16 + l15) * PS + s * 32 + fragoff]);

#pragma unroll
    for (int rep = 0; rep < 2; ++rep) {
        const int n = q * 8 + w + rep * 4;

        bf16x8 alA[3][2];
        if (useWs) {
#pragma unroll
            for (int m = 0; m < 3; ++m)
#pragma unroll
                for (int s = 0; s < 2; ++s)
                    alA[m][s] = ld_frag(&alp[n * AL_N + (m * 16 + l15) * PS + s * 32 + fragoff]);
        } else {
#pragma unroll
            for (int m = 0; m < 3; ++m)
#pragma unroll
                for (int s = 0; s < 2; ++s)
                    alA[m][s] = mk_al_frag(alpha, n, m, s, l15, quad);
        }

        float p[4];
#pragma unroll
        for (int tt = 0; tt < 4; ++tt) {
            bf16x8 whB[2];
            if (useWs) {
                const unsigned short* wpp = &whp[n * WH_N + (tt * 16 + l15) * PS + fragoff];
                whB[0] = ld_frag(wpp);
                whB[1] = ld_frag(wpp + 32);
            } else {
                whB[0] = mk_wh_frag(W, h, n, tt, 0, l15, quad);
                whB[1] = mk_wh_frag(W, h, n, tt, 1, l15, quad);
            }
            float acc = 0.f;
#pragma unroll
            for (int m = 0; m < 3; ++m) {
                f32x4 z = {0.f, 0.f, 0.f, 0.f};
                f32x4 T = mfma16(biA[m][0], whB[0], z);
                T = mfma16(biA[m][1], whB[1], T);
                f32x4 G = mfma16(alA[m][0], b0B[tt][0], z);
                G = mfma16(alA[m][1], b0B[tt][1], G);
                acc += T[0] * G[0] + T[1] * G[1] + T[2] * G[2] + T[3] * G[3];
            }
            p[tt] = acc;
        }
#pragma unroll
        for (int tt = 0; tt < 4; ++tt) {
            p[tt] += __shfl_xor(p[tt], 16, 64);
            p[tt] += __shfl_xor(p[tt], 32, 64);
        }
        float v = (quad == 0) ? p[0] : (quad == 1) ? p[1] : (quad == 2) ? p[2] : p[3];
        out[(b * NN + n) * ED + lane] = v;
    }
}

// ==========================================================================
extern "C" void kernel_launch(void* const* d_in, const int* in_sizes, int n_in,
                              void* d_out, int out_size, void* d_ws, size_t ws_size,
                              hipStream_t stream) {
    const float* B0    = (const float*)d_in[0];  // (256,40,64)
    const float* Bi    = (const float*)d_in[1];  // (256,40,64)
    const float* W     = (const float*)d_in[2];  // (40,64,64)
    const float* alpha = (const float*)d_in[3];  // (40,40,40)
    const float* h     = (const float*)d_in[4];  // (40,64,1)
    float* out = (float*)d_out;                  // (256,40,64)

    const size_t need2 =
        (size_t)(NB * BIP_N + NB * B0T_N + NN * WHP_N + NN * ALP_N) * sizeof(unsigned short);
    if (ws_size >= need2) {
        unsigned short* BiP = (unsigned short*)d_ws;
        unsigned short* B0T = BiP + (size_t)NB * BIP_N;
        unsigned short* whp = B0T + (size_t)NB * B0T_N;
        unsigned short* alp = whp + (size_t)NN * WHP_N;
        gif_prep2<<<NB, 256, 0, stream>>>(B0, Bi, W, alpha, h, BiP, B0T, whp, alp);
        gif_main2<<<10 * NB, 256, 0, stream>>>(BiP, B0T, whp, alp, out);
        return;
    }

    const size_t need1 = (size_t)(NN * WH_N + NN * AL_N) * sizeof(unsigned short);
    const int useWs = (ws_size >= need1) ? 1 : 0;
    unsigned short* whp = (unsigned short*)d_ws;
    unsigned short* alp = whp + (size_t)NN * WH_N;
    if (useWs) {
        gif_prep<<<dim3(NN, 4), 256, 0, stream>>>(W, alpha, h, whp, alp);
    }
    gif_mfma<<<5 * NB, 256, 0, stream>>>(B0, Bi, whp, alp, W, alpha, h, useWs, out);
}

// Round 4
// 92.492 us; speedup vs baseline: 2.3223x; 1.1837x over previous
//
#include <hip/hip_runtime.h>
#include <hip/hip_bf16.h>

// Problem constants
#define NF 40   // fields f
#define NI 40   // in_sub i
#define NN 40   // out_sub n
#define ED 64   // embed D, d
#define NB 256  // batch b

typedef __attribute__((ext_vector_type(8))) short   short8;
typedef __attribute__((ext_vector_type(8))) __bf16  bf16x8;
typedef __attribute__((ext_vector_type(4))) float   f32x4;

__device__ __forceinline__ unsigned short f2bf(float x) {
    union { float f; unsigned u; } v; v.f = x;
    unsigned r = v.u + 0x7FFFu + ((v.u >> 16) & 1u);   // RNE
    return (unsigned short)(r >> 16);
}

__device__ __forceinline__ bf16x8 ld_frag(const unsigned short* p) {
    return __builtin_bit_cast(bf16x8, *(const short8*)p);
}

__device__ __forceinline__ f32x4 mfma16(bf16x8 a, bf16x8 b, f32x4 c) {
    return __builtin_amdgcn_mfma_f32_16x16x32_bf16(a, b, c, 0, 0, 0);
}

// ==========================================================================
// FAST PATH (tier 2): ws layouts (bf16, MFMA-fragment-ready, zero-padded)
//   BiP[b][i(48)][d(64)] = Bi[b][i][d]
//   B0T[b][D(64)][f(64)] = B0[b][f][D]
//   whp[n][D(64)][d(64)] = W[n][D][d]*h[n][d]
//   alp[n][i(48)][f(64)] = alpha[f][i][n]
// ==========================================================================
#define BIP_N (48 * 64)   // 3072
#define B0T_N (64 * 64)   // 4096
#define WHP_N (64 * 64)   // 4096
#define ALP_N (48 * 64)   // 3072

// Prep: 336 blocks x 256 thr, perfectly parallel roles:
//   x <  256        : per-b conversion (BiP coalesced; B0T via LDS transpose)
//   256 <= x < 296  : n = x-256 : whp (coalesced) + zero alp[n] pad region
//   296 <= x < 336  : f = x-296 : alpha slice, COALESCED read, scatter write
__global__ __launch_bounds__(256) void gif_prep3(
        const float* __restrict__ B0, const float* __restrict__ Bi,
        const float* __restrict__ W, const float* __restrict__ alpha,
        const float* __restrict__ h,
        unsigned short* __restrict__ BiP, unsigned short* __restrict__ B0T,
        unsigned short* __restrict__ whp, unsigned short* __restrict__ alp) {
    const int x = blockIdx.x;
    const int t = threadIdx.x;

    if (x < NB) {
        const int b = x;
        __shared__ float sB0[NF][ED + 1];
        for (int idx = t; idx < NF * ED; idx += 256) {
            int f = idx >> 6, D = idx & 63;
            sB0[f][D] = B0[b * NF * ED + idx];
        }
        __syncthreads();
        for (int idx = t; idx < 48 * 64; idx += 256) {
            int i = idx >> 6, d = idx & 63;
            BiP[b * BIP_N + idx] = (i < NI) ? f2bf(Bi[b * NI * ED + i * ED + d])
                                            : (unsigned short)0;
        }
        for (int idx = t; idx < 64 * 64; idx += 256) {
            int D = idx >> 6, f = idx & 63;
            B0T[b * B0T_N + idx] = (f < NF) ? f2bf(sB0[f][D]) : (unsigned short)0;
        }
    } else if (x < NB + NN) {
        const int n = x - NB;
        for (int idx = t; idx < 64 * 64; idx += 256) {       // whp coalesced
            int d = idx & 63;
            whp[n * WHP_N + idx] = f2bf(W[n * ED * ED + idx] * h[n * ED + d]);
        }
        for (int idx = t; idx < 48 * 64; idx += 256) {       // alp pad zeros
            int i = idx >> 6, f = idx & 63;
            if (i >= NI || f >= NF) alp[n * ALP_N + idx] = 0;
        }
    } else {
        const int f = x - NB - NN;
        // read alpha[f][i][n]: contiguous 1600 floats; scatter-write to alp
        for (int idx = t; idx < NI * NN; idx += 256) {
            int i = idx / NN, n = idx - i * NN;
            alp[n * ALP_N + i * 64 + f] = f2bf(alpha[(f * NI + i) * NN + n]);
        }
    }
}

// Main: 256 blocks (one per b) x 512 thr (8 waves), LDS-free.
// Wave w handles n = w + 8*it, it=0..4. Per-b fragments loaded once;
// per-n param fragments double-buffered in registers (prefetch n+8 while
// computing n) so L2 latency is hidden by the 48-MFMA body.
__global__ __launch_bounds__(512, 2) void gif_main3(
        const unsigned short* __restrict__ BiP,
        const unsigned short* __restrict__ B0T,
        const unsigned short* __restrict__ whp,
        const unsigned short* __restrict__ alp,
        float* __restrict__ out) {
    const int b = blockIdx.x;
    const int t = threadIdx.x;
    const int lane = t & 63, w = t >> 6;          // w in 0..7
    const int quad = lane >> 4, l15 = lane & 15, fo = quad * 8;

    const unsigned short* bip = BiP + b * BIP_N;
    const unsigned short* b0t = B0T + b * B0T_N;

    bf16x8 biA[3][2], b0B[4][2];
#pragma unroll
    for (int m = 0; m < 3; ++m)
#pragma unroll
        for (int s = 0; s < 2; ++s)
            biA[m][s] = ld_frag(&bip[(m * 16 + l15) * 64 + s * 32 + fo]);
#pragma unroll
    for (int tt = 0; tt < 4; ++tt)
#pragma unroll
        for (int s = 0; s < 2; ++s)
            b0B[tt][s] = ld_frag(&b0t[(tt * 16 + l15) * 64 + s * 32 + fo]);

    bf16x8 alA[2][3][2], whB[2][4][2];
    {
        const unsigned short* ap = alp + w * ALP_N;
        const unsigned short* wp = whp + w * WHP_N;
#pragma unroll
        for (int m = 0; m < 3; ++m)
#pragma unroll
            for (int s = 0; s < 2; ++s)
                alA[0][m][s] = ld_frag(&ap[(m * 16 + l15) * 64 + s * 32 + fo]);
#pragma unroll
        for (int tt = 0; tt < 4; ++tt)
#pragma unroll
            for (int s = 0; s < 2; ++s)
                whB[0][tt][s] = ld_frag(&wp[(tt * 16 + l15) * 64 + s * 32 + fo]);
    }

#pragma unroll
    for (int it = 0; it < 5; ++it) {
        const int cur = it & 1, nxt = cur ^ 1;
        const int n = w + 8 * it;

        if (it < 4) {   // prefetch next n's fragments into the other buffer
            const unsigned short* ap = alp + (n + 8) * ALP_N;
            const unsigned short* wp = whp + (n + 8) * WHP_N;
#pragma unroll
            for (int m = 0; m < 3; ++m)
#pragma unroll
                for (int s = 0; s < 2; ++s)
                    alA[nxt][m][s] = ld_frag(&ap[(m * 16 + l15) * 64 + s * 32 + fo]);
#pragma unroll
            for (int tt = 0; tt < 4; ++tt)
#pragma unroll
                for (int s = 0; s < 2; ++s)
                    whB[nxt][tt][s] = ld_frag(&wp[(tt * 16 + l15) * 64 + s * 32 + fo]);
        }

        float p[4];
#pragma unroll
        for (int tt = 0; tt < 4; ++tt) {
            float acc = 0.f;
#pragma unroll
            for (int m = 0; m < 3; ++m) {
                f32x4 z = {0.f, 0.f, 0.f, 0.f};
                f32x4 T = mfma16(biA[m][0], whB[cur][tt][0], z);
                T = mfma16(biA[m][1], whB[cur][tt][1], T);
                f32x4 G = mfma16(alA[cur][m][0], b0B[tt][0], z);
                G = mfma16(alA[cur][m][1], b0B[tt][1], G);
                acc += T[0] * G[0] + T[1] * G[1] + T[2] * G[2] + T[3] * G[3];
            }
            p[tt] = acc;
        }
#pragma unroll
        for (int tt = 0; tt < 4; ++tt) {
            p[tt] += __shfl_xor(p[tt], 16, 64);
            p[tt] += __shfl_xor(p[tt], 32, 64);
        }
        float v = (quad == 0) ? p[0] : (quad == 1) ? p[1] : (quad == 2) ? p[2] : p[3];
        out[(b * NN + n) * ED + lane] = v;
    }
}

// ==========================================================================
// FALLBACK (small ws): round-2 verified kernels.
// ==========================================================================
#define PS 72
#define WH_N (ED * PS)
#define AL_N (48 * PS)

__global__ __launch_bounds__(256) void gif_prep(
        const float* __restrict__ W, const float* __restrict__ alpha,
        const float* __restrict__ h,
        unsigned short* __restrict__ whp, unsigned short* __restrict__ alp) {
    const int n = blockIdx.x;
    const int t0 = blockIdx.y * 256 + threadIdx.x;
    for (int idx = t0; idx < ED * PS; idx += 1024) {
        int D = idx / PS, c = idx - D * PS;
        float v = (c < ED) ? W[n * ED * ED + D * ED + c] * h[n * ED + c] : 0.f;
        whp[n * WH_N + idx] = f2bf(v);
    }
    for (int idx = t0; idx < 48 * PS; idx += 1024) {
        int i = idx / PS, c = idx - i * PS;
        float v = (i < NI && c < NF) ? alpha[(c * NI + i) * NN + n] : 0.f;
        alp[n * AL_N + idx] = f2bf(v);
    }
}

__device__ __forceinline__ bf16x8 mk_al_frag(const float* __restrict__ alpha,
        int n, int m, int s, int l15, int quad) {
    bf16x8 r;
    const int row = m * 16 + l15;
    const int f0 = s * 32 + quad * 8;
#pragma unroll
    for (int j = 0; j < 8; ++j) {
        const int f = f0 + j;
        float v = (row < NI && f < NF) ? alpha[(f * NI + row) * NN + n] : 0.f;
        r[j] = (__bf16)v;
    }
    return r;
}
__device__ __forceinline__ bf16x8 mk_wh_frag(const float* __restrict__ W,
        const float* __restrict__ h, int n, int tt, int s, int l15, int quad) {
    bf16x8 r;
    const int row = tt * 16 + l15;
    const int k0 = s * 32 + quad * 8;
#pragma unroll
    for (int j = 0; j < 8; ++j) {
        float v = W[n * ED * ED + row * ED + k0 + j] * h[n * ED + k0 + j];
        r[j] = (__bf16)v;
    }
    return r;
}

__global__ __launch_bounds__(256) void gif_mfma(
        const float* __restrict__ B0, const float* __restrict__ Bi,
        const unsigned short* __restrict__ whp, const unsigned short* __restrict__ alp,
        const float* __restrict__ W, const float* __restrict__ alpha,
        const float* __restrict__ h, int useWs, float* __restrict__ out) {
    const int q = blockIdx.x >> 8;
    const int b = blockIdx.x & 255;

    __shared__ __align__(16) unsigned short sBi[48 * PS];
    __shared__ __align__(16) unsigned short sBT[ED * PS];

    const int t = threadIdx.x;
    for (int idx = t; idx < 48 * PS; idx += 256) {
        int i = idx / PS, c = idx - i * PS;
        sBi[idx] = (i < NI && c < ED) ? f2bf(Bi[b * NI * ED + i * ED + c])
                                      : (unsigned short)0;
    }
    for (int idx = t; idx < ED * PS; idx += 256) {
        int D = idx / PS, c = idx - D * PS;
        sBT[idx] = (c < NF) ? f2bf(B0[b * NF * ED + c * ED + D])
                            : (unsigned short)0;
    }
    __syncthreads();

    const int lane = t & 63, w = t >> 6;
    const int quad = lane >> 4, l15 = lane & 15;
    const int fragoff = quad * 8;

    bf16x8 biA[3][2], b0B[4][2];
#pragma unroll
    for (int m = 0; m < 3; ++m)
#pragma unroll
        for (int s = 0; s < 2; ++s)
            biA[m][s] = ld_frag(&sBi[(m * 16 + l15) * PS + s * 32 + fragoff]);
#pragma unroll
    for (int tt = 0; tt < 4; ++tt)
#pragma unroll
        for (int s = 0; s < 2; ++s)
            b0B[tt][s] = ld_frag(&sBT[(tt * 16 + l15) * PS + s * 32 + fragoff]);

#pragma unroll
    for (int rep = 0; rep < 2; ++rep) {
        const int n = q * 8 + w + rep * 4;

        bf16x8 alA[3][2];
        if (useWs) {
#pragma unroll
            for (int m = 0; m < 3; ++m)
#pragma unroll
                for (int s = 0; s < 2; ++s)
                    alA[m][s] = ld_frag(&alp[n * AL_N + (m * 16 + l15) * PS + s * 32 + fragoff]);
        } else {
#pragma unroll
            for (int m = 0; m < 3; ++m)
#pragma unroll
                for (int s = 0; s < 2; ++s)
                    alA[m][s] = mk_al_frag(alpha, n, m, s, l15, quad);
        }

        float p[4];
#pragma unroll
        for (int tt = 0; tt < 4; ++tt) {
            bf16x8 whB[2];
            if (useWs) {
                const unsigned short* wpp = &whp[n * WH_N + (tt * 16 + l15) * PS + fragoff];
                whB[0] = ld_frag(wpp);
                whB[1] = ld_frag(wpp + 32);
            } else {
                whB[0] = mk_wh_frag(W, h, n, tt, 0, l15, quad);
                whB[1] = mk_wh_frag(W, h, n, tt, 1, l15, quad);
            }
            float acc = 0.f;
#pragma unroll
            for (int m = 0; m < 3; ++m) {
                f32x4 z = {0.f, 0.f, 0.f, 0.f};
                f32x4 T = mfma16(biA[m][0], whB[0], z);
                T = mfma16(biA[m][1], whB[1], T);
                f32x4 G = mfma16(alA[m][0], b0B[tt][0], z);
                G = mfma16(alA[m][1], b0B[tt][1], G);
                acc += T[0] * G[0] + T[1] * G[1] + T[2] * G[2] + T[3] * G[3];
            }
            p[tt] = acc;
        }
#pragma unroll
        for (int tt = 0; tt < 4; ++tt) {
            p[tt] += __shfl_xor(p[tt], 16, 64);
            p[tt] += __shfl_xor(p[tt], 32, 64);
        }
        float v = (quad == 0) ? p[0] : (quad == 1) ? p[1] : (quad == 2) ? p[2] : p[3];
        out[(b * NN + n) * ED + lane] = v;
    }
}

// ==========================================================================
extern "C" void kernel_launch(void* const* d_in, const int* in_sizes, int n_in,
                              void* d_out, int out_size, void* d_ws, size_t ws_size,
                              hipStream_t stream) {
    const float* B0    = (const float*)d_in[0];  // (256,40,64)
    const float* Bi    = (const float*)d_in[1];  // (256,40,64)
    const float* W     = (const float*)d_in[2];  // (40,64,64)
    const float* alpha = (const float*)d_in[3];  // (40,40,40)
    const float* h     = (const float*)d_in[4];  // (40,64,1)
    float* out = (float*)d_out;                  // (256,40,64)

    const size_t need2 =
        (size_t)(NB * BIP_N + NB * B0T_N + NN * WHP_N + NN * ALP_N) * sizeof(unsigned short);
    if (ws_size >= need2) {
        unsigned short* BiP = (unsigned short*)d_ws;
        unsigned short* B0T = BiP + (size_t)NB * BIP_N;
        unsigned short* whp = B0T + (size_t)NB * B0T_N;
        unsigned short* alp = whp + (size_t)NN * WHP_N;
        gif_prep3<<<NB + NN + NF, 256, 0, stream>>>(B0, Bi, W, alpha, h, BiP, B0T, whp, alp);
        gif_main3<<<NB, 512, 0, stream>>>(BiP, B0T, whp, alp, out);
        return;
    }

    const size_t need1 = (size_t)(NN * WH_N + NN * AL_N) * sizeof(unsigned short);
    const int useWs = (ws_size >= need1) ? 1 : 0;
    unsigned short* whp = (unsigned short*)d_ws;
    unsigned short* alp = whp + (size_t)NN * WH_N;
    if (useWs) {
        gif_prep<<<dim3(NN, 4), 256, 0, stream>>>(W, alpha, h, whp, alp);
    }
    gif_mfma<<<5 * NB, 256, 0, stream>>>(B0, Bi, whp, alp, W, alpha, h, useWs, out);
}

// Round 5
// 89.002 us; speedup vs baseline: 2.4134x; 1.0392x over previous
//
#include <hip/hip_runtime.h>
#include <hip/hip_bf16.h>

// Problem constants
#define NF 40   // fields f
#define NI 40   // in_sub i
#define NN 40   // out_sub n
#define ED 64   // embed D, d
#define NB 256  // batch b

typedef __attribute__((ext_vector_type(8))) short   short8;
typedef __attribute__((ext_vector_type(8))) __bf16  bf16x8;
typedef __attribute__((ext_vector_type(4))) float   f32x4;

__device__ __forceinline__ unsigned short f2bf(float x) {
    union { float f; unsigned u; } v; v.f = x;
    unsigned r = v.u + 0x7FFFu + ((v.u >> 16) & 1u);   // RNE
    return (unsigned short)(r >> 16);
}

__device__ __forceinline__ bf16x8 ld_frag(const unsigned short* p) {
    return __builtin_bit_cast(bf16x8, *(const short8*)p);
}

__device__ __forceinline__ f32x4 mfma16(bf16x8 a, bf16x8 b, f32x4 c) {
    return __builtin_amdgcn_mfma_f32_16x16x32_bf16(a, b, c, 0, 0, 0);
}

// ==========================================================================
// FAST PATH (tier 2): ws holds only the n-params (bf16, fragment-ready):
//   whp[n][D(64)][d(64)] = W[n][D][d]*h[n][d]
//   alp[n][i(48)][f(64)] = alpha[f][i][n]   (pads i>=40 / f>=40 -> 0)
// Per-b data is staged in-block (LDS) by the main kernel.
// ==========================================================================
#define WHP_N (64 * 64)   // 4096
#define ALP_N (48 * 64)   // 3072

// Prep: 80 blocks x 256 thr.
//   x <  40 : n = x   : whp (coalesced) + zero alp[n]'s pad region
//   x >= 40 : f = x-40: alpha slice, coalesced read, scatter write
__global__ __launch_bounds__(256) void gif_prep4(
        const float* __restrict__ W, const float* __restrict__ alpha,
        const float* __restrict__ h,
        unsigned short* __restrict__ whp, unsigned short* __restrict__ alp) {
    const int x = blockIdx.x;
    const int t = threadIdx.x;
    if (x < NN) {
        const int n = x;
        for (int idx = t; idx < 64 * 64; idx += 256) {       // whp coalesced
            int d = idx & 63;
            whp[n * WHP_N + idx] = f2bf(W[n * ED * ED + idx] * h[n * ED + d]);
        }
        for (int idx = t; idx < 8 * 64; idx += 256)          // rows i 40..47
            alp[n * ALP_N + (40 + (idx >> 6)) * 64 + (idx & 63)] = 0;
        for (int idx = t; idx < 40 * 24; idx += 256) {       // cols f 40..63
            int i = idx / 24, f = 40 + idx - i * 24;
            alp[n * ALP_N + i * 64 + f] = 0;
        }
    } else {
        const int f = x - NN;
        for (int idx = t; idx < NI * NN; idx += 256) {       // coalesced read
            int i = idx / NN, n = idx - i * NN;
            alp[n * ALP_N + i * 64 + f] = f2bf(alpha[(f * NI + i) * NN + n]);
        }
    }
}

// Main: 512 blocks x 256 thr (4 waves), 2 blocks/CU.
//   q = bx>>8 (n-half: 0 -> n 0..19, 1 -> n 20..39), b = bx&255.
//   Stage Bi[b], B0[b]^T into LDS (PS=72 pad -> ~conflict-free b128 reads),
//   with the first n's param fragments issued to L2 BEFORE staging.
//   Wave w: n = q*20 + it*4 + w, it=0..4; params double-buffered in regs.
#define PSM 72
__global__ __launch_bounds__(256, 2) void gif_main4(
        const float* __restrict__ B0, const float* __restrict__ Bi,
        const unsigned short* __restrict__ whp,
        const unsigned short* __restrict__ alp,
        float* __restrict__ out) {
    const int q = blockIdx.x >> 8;
    const int b = blockIdx.x & 255;
    const int t = threadIdx.x;
    const int lane = t & 63, w = t >> 6;
    const int quad = lane >> 4, l15 = lane & 15, fo = quad * 8;

    __shared__ __align__(16) unsigned short sBi[48 * PSM];  // [i][d]
    __shared__ __align__(16) unsigned short sBT[64 * PSM];  // [D][f]

    // ---- issue first n's param fragment loads (L2) before staging ----
    bf16x8 alA[2][3][2], whB[2][4][2];
    {
        const int n0 = q * 20 + w;
        const unsigned short* ap = alp + n0 * ALP_N;
        const unsigned short* wp = whp + n0 * WHP_N;
#pragma unroll
        for (int m = 0; m < 3; ++m)
#pragma unroll
            for (int s = 0; s < 2; ++s)
                alA[0][m][s] = ld_frag(&ap[(m * 16 + l15) * 64 + s * 32 + fo]);
#pragma unroll
        for (int tt = 0; tt < 4; ++tt)
#pragma unroll
            for (int s = 0; s < 2; ++s)
                whB[0][tt][s] = ld_frag(&wp[(tt * 16 + l15) * 64 + s * 32 + fo]);
    }

    // ---- LDS staging (fp32 -> bf16), all global reads coalesced ----
    {
        const float* bi = Bi + b * NI * ED;
        const float* b0 = B0 + b * NF * ED;
        for (int idx = t; idx < NI * ED; idx += 256) {        // sBi real rows
            int i = idx >> 6, d = idx & 63;
            sBi[i * PSM + d] = f2bf(bi[idx]);
        }
        for (int idx = t; idx < 8 * 64; idx += 256)           // sBi pad rows
            sBi[(40 + (idx >> 6)) * PSM + (idx & 63)] = 0;
        for (int idx = t; idx < NF * ED; idx += 256) {        // sBT transpose
            int f = idx >> 6, D = idx & 63;
            sBT[D * PSM + f] = f2bf(b0[idx]);
        }
        for (int idx = t; idx < 64 * 24; idx += 256) {        // sBT pad cols
            int D = idx / 24, f = 40 + idx - D * 24;
            sBT[D * PSM + f] = 0;
        }
    }
    __syncthreads();

    // ---- per-b fragments from LDS (ds_read_b128, ~2-way = free) ----
    bf16x8 biA[3][2], b0B[4][2];
#pragma unroll
    for (int m = 0; m < 3; ++m)
#pragma unroll
        for (int s = 0; s < 2; ++s)
            biA[m][s] = ld_frag(&sBi[(m * 16 + l15) * PSM + s * 32 + fo]);
#pragma unroll
    for (int tt = 0; tt < 4; ++tt)
#pragma unroll
        for (int s = 0; s < 2; ++s)
            b0B[tt][s] = ld_frag(&sBT[(tt * 16 + l15) * PSM + s * 32 + fo]);

#pragma unroll
    for (int it = 0; it < 5; ++it) {
        const int cur = it & 1, nxt = cur ^ 1;
        const int n = q * 20 + it * 4 + w;

        if (it < 4) {   // prefetch next n's fragments (hidden by MFMA body)
            const unsigned short* ap = alp + (n + 4) * ALP_N;
            const unsigned short* wp = whp + (n + 4) * WHP_N;
#pragma unroll
            for (int m = 0; m < 3; ++m)
#pragma unroll
                for (int s = 0; s < 2; ++s)
                    alA[nxt][m][s] = ld_frag(&ap[(m * 16 + l15) * 64 + s * 32 + fo]);
#pragma unroll
            for (int tt = 0; tt < 4; ++tt)
#pragma unroll
                for (int s = 0; s < 2; ++s)
                    whB[nxt][tt][s] = ld_frag(&wp[(tt * 16 + l15) * 64 + s * 32 + fo]);
        }

        float p[4];
#pragma unroll
        for (int tt = 0; tt < 4; ++tt) {
            float acc = 0.f;
#pragma unroll
            for (int m = 0; m < 3; ++m) {
                f32x4 z = {0.f, 0.f, 0.f, 0.f};
                f32x4 T = mfma16(biA[m][0], whB[cur][tt][0], z);
                T = mfma16(biA[m][1], whB[cur][tt][1], T);
                f32x4 G = mfma16(alA[cur][m][0], b0B[tt][0], z);
                G = mfma16(alA[cur][m][1], b0B[tt][1], G);
                acc += T[0] * G[0] + T[1] * G[1] + T[2] * G[2] + T[3] * G[3];
            }
            p[tt] = acc;
        }
#pragma unroll
        for (int tt = 0; tt < 4; ++tt) {
            p[tt] += __shfl_xor(p[tt], 16, 64);
            p[tt] += __shfl_xor(p[tt], 32, 64);
        }
        float v = (quad == 0) ? p[0] : (quad == 1) ? p[1] : (quad == 2) ? p[2] : p[3];
        out[(b * NN + n) * ED + lane] = v;
    }
}

// ==========================================================================
// FALLBACK (small ws): round-2 verified kernels.
// ==========================================================================
#define PS 72
#define WH_N (ED * PS)
#define AL_N (48 * PS)

__global__ __launch_bounds__(256) void gif_prep(
        const float* __restrict__ W, const float* __restrict__ alpha,
        const float* __restrict__ h,
        unsigned short* __restrict__ whp, unsigned short* __restrict__ alp) {
    const int n = blockIdx.x;
    const int t0 = blockIdx.y * 256 + threadIdx.x;
    for (int idx = t0; idx < ED * PS; idx += 1024) {
        int D = idx / PS, c = idx - D * PS;
        float v = (c < ED) ? W[n * ED * ED + D * ED + c] * h[n * ED + c] : 0.f;
        whp[n * WH_N + idx] = f2bf(v);
    }
    for (int idx = t0; idx < 48 * PS; idx += 1024) {
        int i = idx / PS, c = idx - i * PS;
        float v = (i < NI && c < NF) ? alpha[(c * NI + i) * NN + n] : 0.f;
        alp[n * AL_N + idx] = f2bf(v);
    }
}

__device__ __forceinline__ bf16x8 mk_al_frag(const float* __restrict__ alpha,
        int n, int m, int s, int l15, int quad) {
    bf16x8 r;
    const int row = m * 16 + l15;
    const int f0 = s * 32 + quad * 8;
#pragma unroll
    for (int j = 0; j < 8; ++j) {
        const int f = f0 + j;
        float v = (row < NI && f < NF) ? alpha[(f * NI + row) * NN + n] : 0.f;
        r[j] = (__bf16)v;
    }
    return r;
}
__device__ __forceinline__ bf16x8 mk_wh_frag(const float* __restrict__ W,
        const float* __restrict__ h, int n, int tt, int s, int l15, int quad) {
    bf16x8 r;
    const int row = tt * 16 + l15;
    const int k0 = s * 32 + quad * 8;
#pragma unroll
    for (int j = 0; j < 8; ++j) {
        float v = W[n * ED * ED + row * ED + k0 + j] * h[n * ED + k0 + j];
        r[j] = (__bf16)v;
    }
    return r;
}

__global__ __launch_bounds__(256) void gif_mfma(
        const float* __restrict__ B0, const float* __restrict__ Bi,
        const unsigned short* __restrict__ whp, const unsigned short* __restrict__ alp,
        const float* __restrict__ W, const float* __restrict__ alpha,
        const float* __restrict__ h, int useWs, float* __restrict__ out) {
    const int q = blockIdx.x >> 8;
    const int b = blockIdx.x & 255;

    __shared__ __align__(16) unsigned short sBi[48 * PS];
    __shared__ __align__(16) unsigned short sBT[ED * PS];

    const int t = threadIdx.x;
    for (int idx = t; idx < 48 * PS; idx += 256) {
        int i = idx / PS, c = idx - i * PS;
        sBi[idx] = (i < NI && c < ED) ? f2bf(Bi[b * NI * ED + i * ED + c])
                                      : (unsigned short)0;
    }
    for (int idx = t; idx < ED * PS; idx += 256) {
        int D = idx / PS, c = idx - D * PS;
        sBT[idx] = (c < NF) ? f2bf(B0[b * NF * ED + c * ED + D])
                            : (unsigned short)0;
    }
    __syncthreads();

    const int lane = t & 63, w = t >> 6;
    const int quad = lane >> 4, l15 = lane & 15;
    const int fragoff = quad * 8;

    bf16x8 biA[3][2], b0B[4][2];
#pragma unroll
    for (int m = 0; m < 3; ++m)
#pragma unroll
        for (int s = 0; s < 2; ++s)
            biA[m][s] = ld_frag(&sBi[(m * 16 + l15) * PS + s * 32 + fragoff]);
#pragma unroll
    for (int tt = 0; tt < 4; ++tt)
#pragma unroll
        for (int s = 0; s < 2; ++s)
            b0B[tt][s] = ld_frag(&sBT[(tt * 16 + l15) * PS + s * 32 + fragoff]);

#pragma unroll
    for (int rep = 0; rep < 2; ++rep) {
        const int n = q * 8 + w + rep * 4;

        bf16x8 alA[3][2];
        if (useWs) {
#pragma unroll
            for (int m = 0; m < 3; ++m)
#pragma unroll
                for (int s = 0; s < 2; ++s)
                    alA[m][s] = ld_frag(&alp[n * AL_N + (m * 16 + l15) * PS + s * 32 + fragoff]);
        } else {
#pragma unroll
            for (int m = 0; m < 3; ++m)
#pragma unroll
                for (int s = 0; s < 2; ++s)
                    alA[m][s] = mk_al_frag(alpha, n, m, s, l15, quad);
        }

        float p[4];
#pragma unroll
        for (int tt = 0; tt < 4; ++tt) {
            bf16x8 whB[2];
            if (useWs) {
                const unsigned short* wpp = &whp[n * WH_N + (tt * 16 + l15) * PS + fragoff];
                whB[0] = ld_frag(wpp);
                whB[1] = ld_frag(wpp + 32);
            } else {
                whB[0] = mk_wh_frag(W, h, n, tt, 0, l15, quad);
                whB[1] = mk_wh_frag(W, h, n, tt, 1, l15, quad);
            }
            float acc = 0.f;
#pragma unroll
            for (int m = 0; m < 3; ++m) {
                f32x4 z = {0.f, 0.f, 0.f, 0.f};
                f32x4 T = mfma16(biA[m][0], whB[0], z);
                T = mfma16(biA[m][1], whB[1], T);
                f32x4 G = mfma16(alA[m][0], b0B[tt][0], z);
                G = mfma16(alA[m][1], b0B[tt][1], G);
                acc += T[0] * G[0] + T[1] * G[1] + T[2] * G[2] + T[3] * G[3];
            }
            p[tt] = acc;
        }
#pragma unroll
        for (int tt = 0; tt < 4; ++tt) {
            p[tt] += __shfl_xor(p[tt], 16, 64);
            p[tt] += __shfl_xor(p[tt], 32, 64);
        }
        float v = (quad == 0) ? p[0] : (quad == 1) ? p[1] : (quad == 2) ? p[2] : p[3];
        out[(b * NN + n) * ED + lane] = v;
    }
}

// ==========================================================================
extern "C" void kernel_launch(void* const* d_in, const int* in_sizes, int n_in,
                              void* d_out, int out_size, void* d_ws, size_t ws_size,
                              hipStream_t stream) {
    const float* B0    = (const float*)d_in[0];  // (256,40,64)
    const float* Bi    = (const float*)d_in[1];  // (256,40,64)
    const float* W     = (const float*)d_in[2];  // (40,64,64)
    const float* alpha = (const float*)d_in[3];  // (40,40,40)
    const float* h     = (const float*)d_in[4];  // (40,64,1)
    float* out = (float*)d_out;                  // (256,40,64)

    const size_t need2 = (size_t)(NN * WHP_N + NN * ALP_N) * sizeof(unsigned short);
    if (ws_size >= need2) {
        unsigned short* whp = (unsigned short*)d_ws;
        unsigned short* alp = whp + (size_t)NN * WHP_N;
        gif_prep4<<<NN + NF, 256, 0, stream>>>(W, alpha, h, whp, alp);
        gif_main4<<<2 * NB, 256, 0, stream>>>(B0, Bi, whp, alp, out);
        return;
    }

    const size_t need1 = (size_t)(NN * WH_N + NN * AL_N) * sizeof(unsigned short);
    const int useWs = (ws_size >= need1) ? 1 : 0;
    unsigned short* whp = (unsigned short*)d_ws;
    unsigned short* alp = whp + (size_t)NN * WH_N;
    if (useWs) {
        gif_prep<<<dim3(NN, 4), 256, 0, stream>>>(W, alpha, h, whp, alp);
    }
    gif_mfma<<<5 * NB, 256, 0, stream>>>(B0, Bi, whp, alp, W, alpha, h, useWs, out);
}